// Round 1
// baseline (778.120 us; speedup 1.0000x reference)
//
#include <hip/hip_runtime.h>
#include <cmath>

#define NTOK 32768   // 32*32*32 tokens
#define CF   64      // channels

// ---------------------------------------------------------------------------
// Token selection: d = sqrt(dd) (f32, exact for perfect squares); selected iff
// dd is a perfect square s*s with s % dil == 0 (covers d==0 since 0%dil==0).
// ---------------------------------------------------------------------------
__device__ __forceinline__ bool is_selected(int n, int dil) {
    int z = n >> 10, y = (n >> 5) & 31, x = n & 31;
    int a = z - 16, b = y - 16, c = x - 16;
    int dd = a * a + b * b + c * c;           // <= 768
    int s = (int)(sqrtf((float)dd) + 0.5f);
    if (s * s != dd) return false;
    return (s % dil) == 0;
}

// Build the three ascending index lists into idx_all[di*1024 + ...].
// One block, 256 threads; each thread owns 128 consecutive n (order-stable).
__global__ void build_idx_kernel(int* __restrict__ idx_all) {
    __shared__ int cnt[256];
    int t = threadIdx.x;
    for (int di = 0; di < 3; ++di) {
        int dil = 2 * (di + 1);               // 2, 4, 6
        int base = t * 128;
        int local = 0;
        for (int k = 0; k < 128; ++k) local += is_selected(base + k, dil) ? 1 : 0;
        cnt[t] = local;
        __syncthreads();
        for (int off = 1; off < 256; off <<= 1) {   // Hillis-Steele inclusive scan
            int v = (t >= off) ? cnt[t - off] : 0;
            __syncthreads();
            cnt[t] += v;
            __syncthreads();
        }
        int w = cnt[t] - local;               // exclusive prefix
        for (int k = 0; k < 128; ++k) {
            int n = base + k;
            if (is_selected(n, dil)) idx_all[di * 1024 + (w++)] = n;
        }
        __syncthreads();
    }
}

// ---------------------------------------------------------------------------
// Patch embed: t[n][c] = conv(x, w_patch)[c][n] + b_patch[c] + pos[c][n]
// Block = 256 threads = 4 tokens x 64 channels. w_patch staged transposed in
// LDS ([tap][c] -> lanes read consecutive c: 2-way bank alias, free).
// ---------------------------------------------------------------------------
__global__ void patch_kernel(const float* __restrict__ x,
                             const float* __restrict__ w,
                             const float* __restrict__ bias,
                             const float* __restrict__ pos,
                             float* __restrict__ t) {
    __shared__ float wT[64][64];      // [tap][c], 16 KB
    __shared__ float patch[4][64];    // 4 tokens x 64 taps
    int tid = threadIdx.x;
    for (int k = tid; k < 4096; k += 256) {
        int c = k >> 6, tap = k & 63;
        wT[tap][c] = w[k];            // w is [c][tap] row-major
    }
    int tok0 = blockIdx.x * 4;
    int tl  = tid >> 6;               // local token 0..3 (one wave each)
    int tap = tid & 63;
    int n = tok0 + tl;
    int z = n >> 10, yy = (n >> 5) & 31, xx = n & 31;
    int dz = tap >> 4, dy = (tap >> 2) & 3, dx = tap & 3;
    patch[tl][tap] = x[((z * 4 + dz) * 128 + (yy * 4 + dy)) * 128 + (xx * 4 + dx)];
    __syncthreads();
    int c = tap;
    float acc = bias[c];
    #pragma unroll
    for (int k = 0; k < 64; ++k)
        acc += patch[tl][k] * wT[k][c];   // patch: wave-broadcast; wT: conflict-free
    t[n * 64 + c] = acc + pos[c * NTOK + n];
}

// ---------------------------------------------------------------------------
// Gather + QKV: qkv[i][j] = sum_c t[idx[i]][c] * qkv_w[j][c] + qkv_b[j]
// Block = 192 threads (3 waves) per selected token.
// ---------------------------------------------------------------------------
__global__ void qkv_kernel(const float* __restrict__ t,
                           const float* __restrict__ w,
                           const float* __restrict__ bias,
                           const int* __restrict__ idx,
                           float* __restrict__ qkv) {
    int i = blockIdx.x;
    int j = threadIdx.x;              // 0..191
    __shared__ float tv[64];
    int n = idx[i];
    if (j < 64) tv[j] = t[n * 64 + j];
    __syncthreads();
    float acc = bias[j];
    const float* wr = w + j * 64;
    #pragma unroll
    for (int c = 0; c < 64; ++c) acc += tv[c] * wr[c];
    qkv[i * 192 + j] = acc;
}

// ---------------------------------------------------------------------------
// Attention: one wave (64 threads) per query row i.
// scores -> LDS, shuffle-reduce max/sum, y[i][c] = sum_j softmax_j * v[j][c].
// ---------------------------------------------------------------------------
__global__ void attn_kernel(const float* __restrict__ qkv,
                            float* __restrict__ y, int M) {
    int i = blockIdx.x;
    int lane = threadIdx.x;           // 0..63, one wave
    __shared__ float qs[64];
    __shared__ float p[1024];         // M <= 280
    qs[lane] = qkv[i * 192 + lane];
    __syncthreads();
    const float scale = 0.125f;       // 1/sqrt(64)
    for (int j = lane; j < M; j += 64) {
        const float* kr = qkv + j * 192 + 64;
        float acc = 0.f;
        #pragma unroll
        for (int c = 0; c < 64; ++c) acc += qs[c] * kr[c];
        p[j] = acc * scale;
    }
    __syncthreads();
    float m = -INFINITY;
    for (int j = lane; j < M; j += 64) m = fmaxf(m, p[j]);
    #pragma unroll
    for (int off = 32; off > 0; off >>= 1) m = fmaxf(m, __shfl_xor(m, off));
    float s = 0.f;
    for (int j = lane; j < M; j += 64) { float e = expf(p[j] - m); p[j] = e; s += e; }
    #pragma unroll
    for (int off = 32; off > 0; off >>= 1) s += __shfl_xor(s, off);
    __syncthreads();
    float inv = 1.f / s;
    float acc = 0.f;
    for (int j = 0; j < M; ++j) acc += p[j] * qkv[j * 192 + 128 + lane];
    y[i * 64 + lane] = acc * inv;
}

// ---------------------------------------------------------------------------
// Proj + residual + scatter: t[idx[i]][c] = y[i] . proj_w[c] + proj_b[c] + y[i][c]
// ---------------------------------------------------------------------------
__global__ void proj_kernel(float* __restrict__ t,
                            const float* __restrict__ y,
                            const float* __restrict__ pw,
                            const float* __restrict__ pb,
                            const int* __restrict__ idx) {
    int i = blockIdx.x;
    int c = threadIdx.x;              // 0..63
    __shared__ float yv[64];
    yv[c] = y[i * 64 + c];
    __syncthreads();
    float acc = pb[c] + yv[c];
    const float* wr = pw + c * 64;
    #pragma unroll
    for (int k = 0; k < 64; ++k) acc += yv[k] * wr[k];
    t[idx[i] * 64 + c] = acc;
}

// ---------------------------------------------------------------------------
// Transpose t[n][c] -> h[c][n]  (LDS 64x65 tile, both sides coalesced)
// ---------------------------------------------------------------------------
__global__ void transpose_kernel(const float* __restrict__ t, float* __restrict__ h) {
    __shared__ float tile[64][65];
    int n0 = blockIdx.x * 64;
    int tid = threadIdx.x;            // 256
    int c = tid & 63, r0 = tid >> 6;
    for (int r = r0; r < 64; r += 4)
        tile[r][c] = t[(n0 + r) * 64 + c];
    __syncthreads();
    int r = tid & 63, c0 = tid >> 6;
    for (int cc = c0; cc < 64; cc += 4)
        h[cc * NTOK + n0 + r] = tile[r][cc];
}

// ---------------------------------------------------------------------------
// Trilinear x4 upsample (separable; matches reference lerp index math).
// One block per (c, zo): z-lerp two 32x32 input planes into LDS once, then
// emit 128x128 outputs as coalesced float4 stores. All reuse stays in LDS.
// ---------------------------------------------------------------------------
__global__ void upsample_kernel(const float* __restrict__ h, float* __restrict__ out) {
    int bc = blockIdx.x;
    int c = bc >> 7, zo = bc & 127;
    __shared__ float pz[1024];        // z-lerped plane, 32x32
    __shared__ float wtab[128];
    __shared__ int   itab[128];
    int tid = threadIdx.x;            // 256
    const float scale = (float)(31.0 / 127.0);   // matches jnp f32 math
    if (tid < 128) {
        float p = (float)tid * scale;
        int i0 = (int)floorf(p);
        if (i0 > 31) i0 = 31;
        itab[tid] = i0;
        wtab[tid] = p - (float)i0;
    }
    float pzf = (float)zo * scale;
    int zi0 = (int)floorf(pzf);
    if (zi0 > 31) zi0 = 31;
    int zi1 = min(zi0 + 1, 31);
    float wz = pzf - (float)zi0;
    const float4* pl0 = (const float4*)(h + (c * 32 + zi0) * 1024);
    const float4* pl1 = (const float4*)(h + (c * 32 + zi1) * 1024);
    float4 a = pl0[tid];
    float4 b = pl1[tid];
    float4 r;
    r.x = a.x * (1.f - wz) + b.x * wz;
    r.y = a.y * (1.f - wz) + b.y * wz;
    r.z = a.z * (1.f - wz) + b.z * wz;
    r.w = a.w * (1.f - wz) + b.w * wz;
    ((float4*)pz)[tid] = r;
    __syncthreads();
    float4* o = (float4*)(out + (size_t)(c * 128 + zo) * 16384);
    for (int q = 0; q < 16; ++q) {
        int Q = q * 256 + tid;        // consecutive lanes -> consecutive stores
        int yo = Q >> 5, xq = Q & 31;
        int yi0 = itab[yo];
        float wy = wtab[yo];
        int yi1 = min(yi0 + 1, 31);
        const float* r0 = pz + yi0 * 32;
        const float* r1 = pz + yi1 * 32;
        float vv[4];
        #pragma unroll
        for (int k = 0; k < 4; ++k) {
            int xo = xq * 4 + k;
            int xi0 = itab[xo];
            float wx = wtab[xo];
            int xi1 = min(xi0 + 1, 31);
            float v0 = r0[xi0] * (1.f - wx) + r0[xi1] * wx;
            float v1 = r1[xi0] * (1.f - wx) + r1[xi1] * wx;
            vv[k] = v0 * (1.f - wy) + v1 * wy;
        }
        float4 v; v.x = vv[0]; v.y = vv[1]; v.z = vv[2]; v.w = vv[3];
        o[Q] = v;
    }
}

// ---------------------------------------------------------------------------
extern "C" void kernel_launch(void* const* d_in, const int* in_sizes, int n_in,
                              void* d_out, int out_size, void* d_ws, size_t ws_size,
                              hipStream_t stream) {
    const float* x       = (const float*)d_in[0];
    const float* w_patch = (const float*)d_in[1];
    const float* b_patch = (const float*)d_in[2];
    const float* pos     = (const float*)d_in[3];
    const float* qkv_w[3]  = {(const float*)d_in[4],  (const float*)d_in[8],  (const float*)d_in[12]};
    const float* qkv_b[3]  = {(const float*)d_in[5],  (const float*)d_in[9],  (const float*)d_in[13]};
    const float* proj_w[3] = {(const float*)d_in[6],  (const float*)d_in[10], (const float*)d_in[14]};
    const float* proj_b[3] = {(const float*)d_in[7],  (const float*)d_in[11], (const float*)d_in[15]};
    float* out = (float*)d_out;

    // ws layout (16 MB total): t [0,8MB) ; h [8MB,16MB). qkv/y/idx alias the h
    // region — they are dead before transpose_kernel writes h.
    char* ws = (char*)d_ws;
    if (ws_size < (size_t)(16u << 20)) return;   // loudly fail validation rather than corrupt
    float* t   = (float*)ws;
    float* h   = (float*)(ws + (8u << 20));
    float* qkv = (float*)(ws + (8u << 20));              // <= 1024*192*4 = 768 KB
    float* y   = (float*)(ws + (8u << 20) + (1u << 20)); // <= 256 KB
    int*   idx = (int*)  (ws + (8u << 20) + (2u << 20)); // 3*1024 ints

    // Host-side selected-token counts (deterministic; only used for grid dims,
    // baked into the graph at capture — same every call).
    int M[3];
    for (int di = 0; di < 3; ++di) {
        int dil = 2 * (di + 1), cnt = 0;
        for (int n = 0; n < NTOK; ++n) {
            int z = n >> 10, yy = (n >> 5) & 31, xx = n & 31;
            int a = z - 16, b = yy - 16, c = xx - 16;
            int dd = a * a + b * b + c * c;
            int s = (int)(std::sqrt((double)dd) + 0.5);
            if (s * s == dd && (s % dil) == 0) cnt++;
        }
        M[di] = cnt;   // expected 280 / 64 / 139
    }

    build_idx_kernel<<<1, 256, 0, stream>>>(idx);
    patch_kernel<<<NTOK / 4, 256, 0, stream>>>(x, w_patch, b_patch, pos, t);
    for (int di = 0; di < 3; ++di) {
        qkv_kernel<<<M[di], 192, 0, stream>>>(t, qkv_w[di], qkv_b[di], idx + di * 1024, qkv);
        attn_kernel<<<M[di], 64, 0, stream>>>(qkv, y, M[di]);
        proj_kernel<<<M[di], 64, 0, stream>>>(t, y, proj_w[di], proj_b[di], idx + di * 1024);
    }
    transpose_kernel<<<NTOK / 64, 256, 0, stream>>>(t, h);
    upsample_kernel<<<CF * 128, 256, 0, stream>>>(h, out);
}